// Round 1
// 1021.082 us; speedup vs baseline: 1.0450x; 1.0450x over previous
//
#include <hip/hip_runtime.h>
#include <stdint.h>

typedef unsigned short u16;
typedef short v8s __attribute__((ext_vector_type(8)));   // 8 x bf16 (4 VGPRs)
typedef float v4f __attribute__((ext_vector_type(4)));   // 4 x f32

#define NTOK 4096
#define DDIM 2048
#define HDIM 1792
#define NEXP 8
#define MAXROWS 9216   /* 8192 slots + per-expert pad to 128 */
#define MAXTILE 72

__device__ __forceinline__ u16 f2b(float f) {
    union { float f; uint32_t i; } v; v.f = f;
    uint32_t r = v.i + 0x7fff + ((v.i >> 16) & 1);   // RNE
    return (u16)(r >> 16);
}
__device__ __forceinline__ float silu_f(float x) { return x / (1.f + __expf(-x)); }
__device__ __forceinline__ float b2f(u16 u) {
    union { float f; uint32_t i; } v; v.i = ((uint32_t)u) << 16; return v.f;
}

// async global->LDS, 16B per lane. LDS dest is wave-uniform base + lane*16.
#define AS1 __attribute__((address_space(1)))
#define AS3 __attribute__((address_space(3)))
__device__ __forceinline__ void gload_lds16(const u16* g, u16* l) {
    __builtin_amdgcn_global_load_lds((const AS1 void*)g, (AS3 void*)l, 16, 0, 0);
}

// f32 -> bf16 bulk convert (n % 4 == 0)
__global__ void cvt_kernel(const float* __restrict__ in, u16* __restrict__ out, int n) {
    int i = (blockIdx.x * blockDim.x + threadIdx.x) * 4;
    if (i >= n) return;
    float4 v = *(const float4*)(in + i);
    ushort4 o;
    o.x = f2b(v.x); o.y = f2b(v.y); o.z = f2b(v.z); o.w = f2b(v.w);
    *(ushort4*)(out + i) = o;
}

// ---------------- router: 1 wave per token, all f32 ----------------
__global__ void router_kernel(const float* __restrict__ x, const float* __restrict__ gw,
                              const float* __restrict__ bias,
                              int* __restrict__ topk_idx, float* __restrict__ topk_wt,
                              int* __restrict__ cnt) {
    int wave = threadIdx.x >> 6, lane = threadIdx.x & 63;
    int t = blockIdx.x * 4 + wave;
    float acc[NEXP];
#pragma unroll
    for (int e = 0; e < NEXP; e++) acc[e] = 0.f;
    const float* xr = x + (size_t)t * DDIM;
    for (int i = 0; i < DDIM / 64; i++) {
        int d = i * 64 + lane;
        float xv = xr[d];
#pragma unroll
        for (int e = 0; e < NEXP; e++) acc[e] += xv * gw[e * DDIM + d];
    }
#pragma unroll
    for (int off = 32; off > 0; off >>= 1)
#pragma unroll
        for (int e = 0; e < NEXP; e++) acc[e] += __shfl_xor(acc[e], off, 64);
    if (lane == 0) {
        float s[NEXP], sb[NEXP];
#pragma unroll
        for (int e = 0; e < NEXP; e++) {
            s[e] = 1.f / (1.f + __expf(-acc[e]));
            sb[e] = s[e] + bias[e];
        }
        int i0 = 0;
#pragma unroll
        for (int e = 1; e < NEXP; e++) if (sb[e] > sb[i0]) i0 = e;   // ties -> lowest idx
        int i1 = -1;
#pragma unroll
        for (int e = 0; e < NEXP; e++) {
            if (e == i0) continue;
            if (i1 < 0 || sb[e] > sb[i1]) i1 = e;
        }
        float w0 = s[i0], w1 = s[i1];
        float inv = 1.f / (w0 + w1 + 1e-20f);
        topk_idx[t * 2] = i0; topk_idx[t * 2 + 1] = i1;
        topk_wt[t * 2] = w0 * inv; topk_wt[t * 2 + 1] = w1 * inv;
        atomicAdd(&cnt[i0], 1); atomicAdd(&cnt[i1], 1);
    }
}

__global__ void zero_small(int* cnt, int* cnt2) {
    if (threadIdx.x < NEXP) { cnt[threadIdx.x] = 0; cnt2[threadIdx.x] = 0; }
}

// prefix (128-aligned segments), tile->expert map, init lists to {tok=0, wt=0}
__global__ void setup_kernel(const int* __restrict__ cnt, int* __restrict__ base,
                             int* __restrict__ exp_tile, int* __restrict__ tok_of,
                             float* __restrict__ wt_of) {
    if (threadIdx.x == 0) {
        int b = 0, sb[NEXP + 1];
        for (int e = 0; e < NEXP; e++) { sb[e] = b; base[e] = b; b += (cnt[e] + 127) & ~127; }
        sb[NEXP] = b; base[NEXP] = b;
        int ntile = b >> 7;
        for (int td = 0; td < MAXTILE; td++) {
            int e = -1;
            if (td < ntile) {
                int r = td << 7;
                for (int q = 0; q < NEXP; q++)
                    if (r >= sb[q] && r < sb[q + 1]) e = q;
            }
            exp_tile[td] = e;
        }
    }
    __syncthreads();
    for (int i = threadIdx.x; i < MAXROWS; i += blockDim.x) { tok_of[i] = 0; wt_of[i] = 0.f; }
}

__global__ void assign_kernel(const int* __restrict__ topk_idx, const float* __restrict__ topk_wt,
                              const int* __restrict__ base, int* __restrict__ cnt2,
                              int* __restrict__ tok_of, float* __restrict__ wt_of) {
    int g = blockIdx.x * blockDim.x + threadIdx.x;   // 0..8191
    int t = g >> 1, k = g & 1;
    int e = topk_idx[t * 2 + k];
    int p = base[e] + atomicAdd(&cnt2[e], 1);
    tok_of[p] = t; wt_of[p] = topk_wt[t * 2 + k];
}

// ---------------- GEMM NT: C[M,N] = A[M,K] @ B[N,K]^T, fp32 accum ------------
// A is bf16 always (async-staged via global_load_lds, 16B/lane).
// B is bf16 (BF32=false, async-staged) or f32 converted on the fly (BF32=true).
// 128x128x64 tile, 256 thr (4 waves 2x2, 64x64/wave as 4x4 16x16 frags).
// LDS layout: row-major 128x64 u16; 16B chunk at LDS slot s of row holds global
// col-chunk cc = s ^ (row&7) (XOR bank swizzle). global_load_lds writes LDS
// linearly, so the swizzle is applied to the per-lane GLOBAL source address
// (rule: linear dest + inverse-swizzled source + swizzle on read).
// EPI: 0 = store bf16, 1 = store f32, 2 = atomicAdd f32 into Cout[tok_of[row]]
template <int EPI, bool GATHER, bool EXPB, bool BF32>
__global__ __launch_bounds__(256, 2)
void gemm_nt(const u16* __restrict__ A, const void* __restrict__ Bw,
             void* __restrict__ Cout, int N, int K,
             const int* __restrict__ tok_of, const int* __restrict__ exp_tile,
             long bstride) {
    int nt = blockIdx.x, mt = blockIdx.y;
    size_t boff = 0;
    if (EXPB) {
        int e = exp_tile[mt];
        if (e < 0) return;                       // unused padded tile
        boff = (size_t)e * bstride;
    }
    int m0 = mt * 128, n0 = nt * 128;
    __shared__ u16 As[128 * 64];
    __shared__ u16 Bs[128 * 64];
    int tid = threadIdx.x, lane = tid & 63, wave = tid >> 6;
    int wm = wave >> 1, wn = wave & 1;
    int quad = lane >> 4, lr = lane & 15;

    v4f acc[4][4];
#pragma unroll
    for (int i = 0; i < 4; i++)
#pragma unroll
        for (int j = 0; j < 4; j++) acc[i][j] = (v4f){0.f, 0.f, 0.f, 0.f};

    // Per-thread staging descriptors, hoisted out of the K loop.
    // Linear chunk idx = j*256 + tid; row = idx>>3; LDS slot s = idx&7;
    // source col-chunk cc = s ^ (row&7).
    const u16* gA[4];          // bf16 A source base (k0 = 0)
    const u16* gB[4];          // bf16 B source base (BF32=false)
    const float* fB[4];        // f32 B source base (BF32=true)
    u16* sB[4];                // per-lane LDS dest for reg-staged B (== linear chunk)
    u16* lA[4];                // wave-uniform LDS dest base for async A
    u16* lB[4];                // wave-uniform LDS dest base for async B
#pragma unroll
    for (int j = 0; j < 4; j++) {
        int idx = j * 256 + tid;
        int row = idx >> 3, s = idx & 7, cc = s ^ (row & 7);
        int arow = GATHER ? tok_of[m0 + row] : (m0 + row);
        gA[j] = A + (size_t)arow * K + cc * 8;
        if (!BF32) {
            gB[j] = (const u16*)Bw + boff + (size_t)(n0 + row) * K + cc * 8;
            fB[j] = nullptr; sB[j] = nullptr;
        } else {
            gB[j] = nullptr;
            fB[j] = (const float*)Bw + boff + (size_t)(n0 + row) * K + cc * 8;
            sB[j] = Bs + (size_t)idx * 8;        // linear == row*64 + s*8
        }
        int cb = (j * 256 + wave * 64) * 8;      // wave-uniform (j, wave uniform)
        lA[j] = As + cb;
        lB[j] = Bs + cb;
    }

    for (int k0 = 0; k0 < K; k0 += 64) {
        // stage 128x64 A tile: 8 async 1KB/wave copies per wave
#pragma unroll
        for (int j = 0; j < 4; j++) gload_lds16(gA[j] + k0, lA[j]);
        if (!BF32) {
#pragma unroll
            for (int j = 0; j < 4; j++) gload_lds16(gB[j] + k0, lB[j]);
        } else {
#pragma unroll
            for (int j = 0; j < 4; j++) {
                const float* bp = fB[j] + k0;
                float4 f0 = *(const float4*)bp;
                float4 f1 = *(const float4*)(bp + 4);
                union { v8s v; u16 s[8]; } u;
                u.s[0] = f2b(f0.x); u.s[1] = f2b(f0.y); u.s[2] = f2b(f0.z); u.s[3] = f2b(f0.w);
                u.s[4] = f2b(f1.x); u.s[5] = f2b(f1.y); u.s[6] = f2b(f1.z); u.s[7] = f2b(f1.w);
                *(v8s*)sB[j] = u.v;
            }
        }
        __syncthreads();                         // compiler drains vmcnt/lgkmcnt here
#pragma unroll
        for (int kk = 0; kk < 64; kk += 32) {
            v8s af[4], bfr[4];
#pragma unroll
            for (int mi = 0; mi < 4; mi++) {
                int row = wm * 64 + mi * 16 + lr;
                int c = (kk >> 3) + quad;
                af[mi] = *(const v8s*)(As + row * 64 + ((c ^ (row & 7)) << 3));
            }
#pragma unroll
            for (int ni = 0; ni < 4; ni++) {
                int row = wn * 64 + ni * 16 + lr;
                int c = (kk >> 3) + quad;
                bfr[ni] = *(const v8s*)(Bs + row * 64 + ((c ^ (row & 7)) << 3));
            }
#pragma unroll
            for (int mi = 0; mi < 4; mi++)
#pragma unroll
                for (int ni = 0; ni < 4; ni++)
                    acc[mi][ni] = __builtin_amdgcn_mfma_f32_16x16x32_bf16(af[mi], bfr[ni], acc[mi][ni], 0, 0, 0);
        }
        __syncthreads();
    }

#pragma unroll
    for (int mi = 0; mi < 4; mi++)
#pragma unroll
        for (int ni = 0; ni < 4; ni++)
#pragma unroll
            for (int r = 0; r < 4; r++) {
                int gr = m0 + wm * 64 + mi * 16 + quad * 4 + r;
                int gc = n0 + wn * 64 + ni * 16 + lr;
                float v = acc[mi][ni][r];
                if (EPI == 0) {
                    ((u16*)Cout)[(size_t)gr * N + gc] = f2b(v);
                } else if (EPI == 1) {
                    ((float*)Cout)[(size_t)gr * N + gc] = v;
                } else {
                    int tok = tok_of[gr];        // pad rows: tok=0, v==0 -> harmless
                    atomicAdd(&((float*)Cout)[(size_t)tok * N + gc], v);
                }
            }
}

// h = silu(w*u1) * (w*u3), written IN PLACE into u1. per-row w (nullptr -> 1).
__global__ void swiglu_kernel(u16* __restrict__ u1, const u16* __restrict__ u3,
                              const float* __restrict__ wt_of) {
    int row = blockIdx.x;
    float w = wt_of ? wt_of[row] : 1.f;
    size_t i = (size_t)row * HDIM + threadIdx.x * 4;
    ushort4 a = *(const ushort4*)(u1 + i);
    ushort4 b = *(const ushort4*)(u3 + i);
    ushort4 o;
    o.x = f2b(silu_f(w * b2f(a.x)) * (w * b2f(b.x)));
    o.y = f2b(silu_f(w * b2f(a.y)) * (w * b2f(b.y)));
    o.z = f2b(silu_f(w * b2f(a.z)) * (w * b2f(b.z)));
    o.w = f2b(silu_f(w * b2f(a.w)) * (w * b2f(b.w)));
    *(ushort4*)(u1 + i) = o;
}

__global__ void aux_kernel(float* __restrict__ out) {
    if (threadIdx.x == 0) out[(size_t)NTOK * DDIM] = 0.f;   // aux_loss
}

extern "C" void kernel_launch(void* const* d_in, const int* in_sizes, int n_in,
                              void* d_out, int out_size, void* d_ws, size_t ws_size,
                              hipStream_t stream) {
    const float* x   = (const float*)d_in[0];
    const float* gw  = (const float*)d_in[1];
    const float* w1s = (const float*)d_in[2];
    const float* w2s = (const float*)d_in[3];
    const float* w3s = (const float*)d_in[4];
    const float* w1e = (const float*)d_in[5];
    const float* w2e = (const float*)d_in[6];
    const float* w3e = (const float*)d_in[7];
    const float* ebias = (const float*)d_in[8];
    float* outp = (float*)d_out;

    char* ws = (char*)d_ws;
    size_t off = 0;
    auto alloc = [&](size_t bytes) {
        void* p = ws + off;
        off = (off + bytes + 255) & ~(size_t)255;
        return p;
    };
    // always-needed region
    u16* xb     = (u16*)alloc((size_t)NTOK * DDIM * 2);          // 16.8 MB
    u16* u1     = (u16*)alloc((size_t)MAXROWS * HDIM * 2);       // 31.5 MB (h in-place)
    u16* u3     = (u16*)alloc((size_t)MAXROWS * HDIM * 2);       // 31.5 MB
    int* topk_idx = (int*)alloc(NTOK * 2 * 4);
    float* topk_wt = (float*)alloc(NTOK * 2 * 4);
    int* cnt    = (int*)alloc(64);
    int* cnt2   = (int*)alloc(64);
    int* base   = (int*)alloc(64);
    int* exp_tile = (int*)alloc(MAXTILE * 4);
    int* tok_of = (int*)alloc(MAXROWS * 4);
    float* wt_of = (float*)alloc(MAXROWS * 4);
    // optional bf16 weight copies (used only if workspace is big enough)
    const int SH = HDIM * DDIM;                  // 3670016
    const long EX = (long)NEXP * HDIM * DDIM;    // 29360128
    u16* w1sb = (u16*)alloc((size_t)SH * 2);
    u16* w2sb = (u16*)alloc((size_t)SH * 2);
    u16* w3sb = (u16*)alloc((size_t)SH * 2);
    u16* w1eb = (u16*)alloc((size_t)EX * 2);
    u16* w2eb = (u16*)alloc((size_t)EX * 2);
    u16* w3eb = (u16*)alloc((size_t)EX * 2);
    bool full = (off <= ws_size);
    (void)in_sizes; (void)n_in; (void)out_size;

    zero_small<<<1, 64, 0, stream>>>(cnt, cnt2);
    router_kernel<<<NTOK / 4, 256, 0, stream>>>(x, gw, ebias, topk_idx, topk_wt, cnt);
    setup_kernel<<<1, 256, 0, stream>>>(cnt, base, exp_tile, tok_of, wt_of);
    assign_kernel<<<NTOK * 2 / 256, 256, 0, stream>>>(topk_idx, topk_wt, base, cnt2, tok_of, wt_of);

    // convert x always; weights only if they fit
    cvt_kernel<<<(NTOK * DDIM / 4 + 255) / 256, 256, 0, stream>>>(x, xb, NTOK * DDIM);
    if (full) {
        cvt_kernel<<<(SH / 4 + 255) / 256, 256, 0, stream>>>(w1s, w1sb, SH);
        cvt_kernel<<<(SH / 4 + 255) / 256, 256, 0, stream>>>(w2s, w2sb, SH);
        cvt_kernel<<<(SH / 4 + 255) / 256, 256, 0, stream>>>(w3s, w3sb, SH);
        cvt_kernel<<<((int)(EX / 4) + 255) / 256, 256, 0, stream>>>(w1e, w1eb, (int)EX);
        cvt_kernel<<<((int)(EX / 4) + 255) / 256, 256, 0, stream>>>(w2e, w2eb, (int)EX);
        cvt_kernel<<<((int)(EX / 4) + 255) / 256, 256, 0, stream>>>(w3e, w3eb, (int)EX);
    }

    if (full) {
        // ---- shared expert (bf16 weights) ----
        gemm_nt<0, false, false, false><<<dim3(HDIM / 128, NTOK / 128), 256, 0, stream>>>(
            xb, w1sb, u1, HDIM, DDIM, nullptr, nullptr, 0);
        gemm_nt<0, false, false, false><<<dim3(HDIM / 128, NTOK / 128), 256, 0, stream>>>(
            xb, w3sb, u3, HDIM, DDIM, nullptr, nullptr, 0);
        swiglu_kernel<<<NTOK, 448, 0, stream>>>(u1, u3, nullptr);
        gemm_nt<1, false, false, false><<<dim3(DDIM / 128, NTOK / 128), 256, 0, stream>>>(
            u1, w2sb, outp, DDIM, HDIM, nullptr, nullptr, 0);
        // ---- routed experts ----
        gemm_nt<0, true, true, false><<<dim3(HDIM / 128, MAXTILE), 256, 0, stream>>>(
            xb, w1eb, u1, HDIM, DDIM, tok_of, exp_tile, (long)HDIM * DDIM);
        gemm_nt<0, true, true, false><<<dim3(HDIM / 128, MAXTILE), 256, 0, stream>>>(
            xb, w3eb, u3, HDIM, DDIM, tok_of, exp_tile, (long)HDIM * DDIM);
        swiglu_kernel<<<MAXROWS, 448, 0, stream>>>(u1, u3, wt_of);
        gemm_nt<2, false, true, false><<<dim3(DDIM / 128, MAXTILE), 256, 0, stream>>>(
            u1, w2eb, outp, DDIM, HDIM, tok_of, exp_tile, (long)DDIM * HDIM);
    } else {
        // ---- same pipeline, f32 B weights converted during staging ----
        gemm_nt<0, false, false, true><<<dim3(HDIM / 128, NTOK / 128), 256, 0, stream>>>(
            xb, w1s, u1, HDIM, DDIM, nullptr, nullptr, 0);
        gemm_nt<0, false, false, true><<<dim3(HDIM / 128, NTOK / 128), 256, 0, stream>>>(
            xb, w3s, u3, HDIM, DDIM, nullptr, nullptr, 0);
        swiglu_kernel<<<NTOK, 448, 0, stream>>>(u1, u3, nullptr);
        gemm_nt<1, false, false, true><<<dim3(DDIM / 128, NTOK / 128), 256, 0, stream>>>(
            u1, w2s, outp, DDIM, HDIM, nullptr, nullptr, 0);
        gemm_nt<0, true, true, true><<<dim3(HDIM / 128, MAXTILE), 256, 0, stream>>>(
            xb, w1e, u1, HDIM, DDIM, tok_of, exp_tile, (long)HDIM * DDIM);
        gemm_nt<0, true, true, true><<<dim3(HDIM / 128, MAXTILE), 256, 0, stream>>>(
            xb, w3e, u3, HDIM, DDIM, tok_of, exp_tile, (long)HDIM * DDIM);
        swiglu_kernel<<<MAXROWS, 448, 0, stream>>>(u1, u3, wt_of);
        gemm_nt<2, false, true, true><<<dim3(DDIM / 128, MAXTILE), 256, 0, stream>>>(
            u1, w2e, outp, DDIM, HDIM, tok_of, exp_tile, (long)DDIM * HDIM);
    }

    aux_kernel<<<1, 64, 0, stream>>>(outp);
}